// Round 6
// baseline (138.720 us; speedup 1.0000x reference)
//
#include <hip/hip_runtime.h>

// (B,N,DIN,DE,NH,DK) = (4,256,128,64,8,16). Inputs f32, output f32.
#define BB   4
#define NN   256
#define DIN  128
#define DE   64
#define NH   8
#define DK   16
#define CC   128   // NH*DK

typedef __attribute__((ext_vector_type(8))) short short8;   // 8 bf16 = 4 VGPRs
typedef __attribute__((ext_vector_type(4))) float f32x4;

// f32 -> bf16 bits, round-to-nearest-even (round-4-verified numerics)
__device__ __forceinline__ unsigned short f2bfu(float f) {
    union { float f; unsigned int i; } v; v.f = f;
    unsigned int x = v.i;
    x += 0x7FFFu + ((x >> 16) & 1u);
    return (unsigned short)(x >> 16);
}

// ---------------------------------------------------------------------------
// prep: blocks [0,256) do QKV (4 rows per block, verified structure);
//       blocks [256,264) do the one-time WE/WE2 f32->bf16 B-fragment prep.
// wfrag[((m*8+g)*2+ks)*64 + lane] = short8 { W[ks*32+q4*8+ii][g*16+l15] }
// ---------------------------------------------------------------------------
__global__ __launch_bounds__(256) void prep_kernel(
    const float* __restrict__ h, const float* __restrict__ WQ,
    const float* __restrict__ WK, const float* __restrict__ WV,
    const float* __restrict__ WE, const float* __restrict__ WE2,
    float* __restrict__ Qw, float* __restrict__ Kw, float* __restrict__ Vw,
    unsigned short* __restrict__ wfrag)
{
    __shared__ float hsh[4 * DIN];       // 2 KB
    __shared__ float psum[4 * 1536];     // 24 KB
    const int t = threadIdx.x;

    if (blockIdx.x >= 256) {
        // ---- W-frag prep (8 blocks x 256 thr = 2048 threads) ----
        const int tid  = (blockIdx.x - 256) * 256 + t;
        const int m    = tid >> 10;
        const int g    = (tid >> 7) & 7;
        const int ks   = (tid >> 6) & 1;
        const int lane = tid & 63;
        const int q4 = lane >> 4, l15 = lane & 15;
        const float* W = m ? WE2 : WE;
        union { uint4 u; unsigned short s[8]; } pk;
        #pragma unroll
        for (int ii = 0; ii < 8; ++ii) {
            const int d = ks * 32 + q4 * 8 + ii;
            pk.s[ii] = f2bfu(W[d * CC + g * 16 + l15]);
        }
        ((uint4*)wfrag)[tid] = pk.u;
        return;
    }

    // ---- QKV: 4 rows per block ----
    const int r0 = blockIdx.x * 4;
    hsh[t]       = h[(size_t)r0 * DIN + t];
    hsh[256 + t] = h[(size_t)r0 * DIN + 256 + t];
    __syncthreads();

    const int cp  = t & 63;              // channel pair: c = 2cp, 2cp+1
    const int qtr = t >> 6;              // d in [qtr*32, qtr*32+32)
    float aq[4][2], ak[4][2], av[4][2];
    #pragma unroll
    for (int r = 0; r < 4; ++r) {
        aq[r][0]=aq[r][1]=ak[r][0]=ak[r][1]=av[r][0]=av[r][1]=0.f;
    }
    #pragma unroll 4
    for (int dd = 0; dd < 32; ++dd) {
        const int d = qtr * 32 + dd;
        const float2 fq = ((const float2*)WQ)[d * 64 + cp];
        const float2 fk = ((const float2*)WK)[d * 64 + cp];
        const float2 fv = ((const float2*)WV)[d * 64 + cp];
        #pragma unroll
        for (int r = 0; r < 4; ++r) {
            const float hd = hsh[r * DIN + d];
            aq[r][0] = fmaf(hd, fq.x, aq[r][0]); aq[r][1] = fmaf(hd, fq.y, aq[r][1]);
            ak[r][0] = fmaf(hd, fk.x, ak[r][0]); ak[r][1] = fmaf(hd, fk.y, ak[r][1]);
            av[r][0] = fmaf(hd, fv.x, av[r][0]); av[r][1] = fmaf(hd, fv.y, av[r][1]);
        }
    }
    float* pq = psum + qtr * 1536;
    #pragma unroll
    for (int r = 0; r < 4; ++r) {
        pq[r*384       + 2*cp] = aq[r][0]; pq[r*384       + 2*cp+1] = aq[r][1];
        pq[r*384 + 128 + 2*cp] = ak[r][0]; pq[r*384 + 128 + 2*cp+1] = ak[r][1];
        pq[r*384 + 256 + 2*cp] = av[r][0]; pq[r*384 + 256 + 2*cp+1] = av[r][1];
    }
    __syncthreads();
    #pragma unroll
    for (int k = 0; k < 6; ++k) {
        const int o = k * 256 + t;               // 0..1535
        float v = psum[o] + psum[1536 + o] + psum[3072 + o] + psum[4608 + o];
        const int r   = o / 384;
        const int mc  = o - r * 384;
        const int mat = mc >> 7;
        const int c   = mc & 127;
        const size_t idx = (size_t)(r0 + r) * CC + c;
        if      (mat == 0) Qw[idx] = v;
        else if (mat == 1) Kw[idx] = v * 0.25f;  // DK^-0.5
        else               Vw[idx] = v;
    }
}

// ---------------------------------------------------------------------------
// Fused attention, 8-WAVE version. One block (512 thr) per (b,i); ONE HEAD
// PER WAVE (g = wave). ROUND-5 POST-MORTEM: source-level load batching left
// the compiled schedule byte-identical (VGPR 84, dur 44us unchanged) — the
// schedule is not controllable from source. The untried structural lever is
// occupancy: profile is latency-bound (MfmaUtil 7 / VALU 26 / HBM 11%) with
// only 12 waves/CU. Same 43.5 KB LDS still allows 3 blocks/CU, so 8 waves
// per block doubles residency to 24 waves/CU. Per-wave state halves (4
// bfrags, scalar acc/dnm), so the (512,6) 85-VGPR cap should hold without
// spill (spill signature: WRITE_SIZE ballooning -> revert to (512,4)).
//
// MFMA 16x16x32 bf16 layouts (HW-verified):
//   A: lane holds A[m=lane&15][k=(lane>>4)*8+ii]
//   B: lane holds B[k=(lane>>4)*8+ii][n=lane&15]
//   C/D: col=lane&15, row=(lane>>4)*4+reg
// ---------------------------------------------------------------------------
__global__ __launch_bounds__(512, 6) void attn_kernel(
    const float* __restrict__ e, const float* __restrict__ maskp,
    const unsigned short* __restrict__ wfrag,
    const float* __restrict__ Qw, const float* __restrict__ Kw,
    const float* __restrict__ Vw, float* __restrict__ out)
{
    __shared__ __align__(16) unsigned short esh[NN * DE];  // 32 KB, swizzled
    __shared__ float qk_sh[NN * 9];                        // 9 KB, pad 9
    __shared__ float msk_sh[NN];
    __shared__ float qrow_sh[CC];

    const int row  = blockIdx.x;
    const int b    = row >> 8, i = row & 255;
    const int t    = threadIdx.x;
    const int wave = t >> 6, lane = t & 63;
    const int q4   = lane >> 4;
    const int l15  = lane & 15;

    // --- stage e[b,i,:,:] f32 -> bf16, XOR-swizzled 16B chunks ---
    // 2048 chunks / 512 threads = 4 iterations (8 loads in flight).
    {
        const float4* src = (const float4*)(e + (size_t)row * NN * DE);
        uint4* dst = (uint4*)esh;
        #pragma unroll
        for (int r = 0; r < 4; ++r) {
            const int cidx = r * 512 + t;        // chunk 0..2047
            const int j = cidx >> 3, ch = cidx & 7;
            const float4 f0 = src[2 * cidx];
            const float4 f1 = src[2 * cidx + 1];
            union { uint4 u; unsigned short s[8]; } pk;
            pk.s[0]=f2bfu(f0.x); pk.s[1]=f2bfu(f0.y); pk.s[2]=f2bfu(f0.z); pk.s[3]=f2bfu(f0.w);
            pk.s[4]=f2bfu(f1.x); pk.s[5]=f2bfu(f1.y); pk.s[6]=f2bfu(f1.z); pk.s[7]=f2bfu(f1.w);
            dst[j * 8 + (ch ^ (j & 7))] = pk.u;
        }
    }
    if (t < CC) qrow_sh[t] = Qw[(size_t)row * CC + t];
    if (t < NN) msk_sh[t] = maskp[b * NN + t];

    // --- B-fragments straight from global (L2-hot): one head (g=wave) ---
    short8 bfragE[2], bfragS[2];
    {
        const uint4* wf = (const uint4*)wfrag;
        #pragma unroll
        for (int ks = 0; ks < 2; ++ks) {
            union { uint4 u; short8 s8; } cv;
            cv.u = wf[((0 * 8 + wave) * 2 + ks) * 64 + lane];   // WE
            bfragE[ks] = cv.s8;
            cv.u = wf[((1 * 8 + wave) * 2 + ks) * 64 + lane];   // WE2
            bfragS[ks] = cv.s8;
        }
    }
    __syncthreads();

    // --- qk[j,h], full f32: thread t -> row j = t&255, 4 heads ---
    {
        const int j  = t & 255;
        const int hb = (t >> 8) * 4;            // heads hb..hb+3
        const float4* kr = (const float4*)(Kw + (size_t)(b * NN + j) * CC);
        #pragma unroll
        for (int hh = 0; hh < 4; ++hh) {
            const int hgl = hb + hh;
            float s = 0.f;
            #pragma unroll
            for (int p = 0; p < 4; ++p) {
                const float4 kv = kr[hgl * 4 + p];
                const int qb = hgl * 16 + p * 4;
                s += kv.x * qrow_sh[qb]     + kv.y * qrow_sh[qb + 1]
                   + kv.z * qrow_sh[qb + 2] + kv.w * qrow_sh[qb + 3];
            }
            qk_sh[j * 9 + hgl] = s;
        }
    }
    __syncthreads();

    const float mi = msk_sh[i];
    float acc = 0.f, dnm = 0.f;
    const short8* ep = (const short8*)esh;
    const int g = wave;                          // this wave's head

    #pragma unroll 2
    for (int s = 0; s < 16; ++s) {
        const int ja = s * 16 + l15;
        const short8 a0 = ep[ja * 8 + ((q4    ) ^ (ja & 7))];  // d 0..31
        const short8 a1 = ep[ja * 8 + ((q4 + 4) ^ (ja & 7))];  // d 32..63

        float vv[4], qk[4], mm[4], mm2[4];
        {
            const float* vrow = Vw + (size_t)(b*NN + s*16 + q4*4) * CC + g*16 + l15;
            #pragma unroll
            for (int r = 0; r < 4; ++r) vv[r] = vrow[r * CC];
        }
        #pragma unroll
        for (int r = 0; r < 4; ++r) {
            const int jr = s * 16 + q4 * 4 + r;
            qk[r] = qk_sh[jr * 9 + g];
            const float m = mi * msk_sh[jr];
            mm[r] = m; mm2[r] = m * m;
        }

        f32x4 s2 = {0.f,0.f,0.f,0.f}, eE = {0.f,0.f,0.f,0.f};
        s2 = __builtin_amdgcn_mfma_f32_16x16x32_bf16(a0, bfragS[0], s2, 0,0,0);
        s2 = __builtin_amdgcn_mfma_f32_16x16x32_bf16(a1, bfragS[1], s2, 0,0,0);
        eE = __builtin_amdgcn_mfma_f32_16x16x32_bf16(a0, bfragE[0], eE, 0,0,0);
        eE = __builtin_amdgcn_mfma_f32_16x16x32_bf16(a1, bfragE[1], eE, 0,0,0);

        #pragma unroll
        for (int r = 0; r < 4; ++r) {
            float sc = qk[r] + s2[r];
            sc = fminf(5.f, fmaxf(-5.f, sc));
            const float p = __expf(sc);
            dnm += p * mm[r];                              // mask^1 -> denom
            acc = fmaf(p * mm2[r], vv[r] + eE[r], acc);    // mask^2
        }
    }

    // reduce over quad groups (lanes l, l^16, l^32, l^48 share a column)
    acc += __shfl_xor(acc, 16); acc += __shfl_xor(acc, 32);
    dnm += __shfl_xor(dnm, 16); dnm += __shfl_xor(dnm, 32);
    if (lane < 16) {
        out[(size_t)row * CC + g * 16 + lane] = acc / fmaxf(dnm, 1e-6f);
    }
}

extern "C" void kernel_launch(void* const* d_in, const int* in_sizes, int n_in,
                              void* d_out, int out_size, void* d_ws, size_t ws_size,
                              hipStream_t stream)
{
    const float* h    = (const float*)d_in[0];
    const float* e    = (const float*)d_in[1];
    const float* mask = (const float*)d_in[2];
    const float* WQ   = (const float*)d_in[3];
    const float* WK   = (const float*)d_in[4];
    const float* WV   = (const float*)d_in[5];
    const float* WE   = (const float*)d_in[6];
    const float* WE2  = (const float*)d_in[7];

    unsigned short* wfrag = (unsigned short*)d_ws;          // 32 KB
    float* Qw = (float*)((char*)d_ws + 32768);              // B*N*C f32 each
    float* Kw = Qw + BB * NN * CC;
    float* Vw = Kw + BB * NN * CC;                          // total ~1.53 MB

    prep_kernel<<<264, 256, 0, stream>>>(h, WQ, WK, WV, WE, WE2,
                                         Qw, Kw, Vw, wfrag);
    attn_kernel<<<BB*NN, 512, 0, stream>>>(e, mask, wfrag, Qw, Kw, Vw,
                                           (float*)d_out);
}